// Round 13
// baseline (269.713 us; speedup 1.0000x reference)
//
#include <hip/hip_runtime.h>
#include <math.h>

// PinSAGE fused pipeline, r13: k1/k5 = zero-LDS zero-barrier wave-autonomous
// GEMM, W pre-shuffled to fragment-linear layout (L1-resident, coalesced),
// ~70 live regs -> lb(256,6) -> 24 waves/CU. k3/agg = r5 proven kernels.
// D=U=E=128, T=20 fixed; N, V from in_sizes.
//
// K0 prep:  WqF/WnF/WgF = bf16 FRAGMENT-LINEAR weights:
//             WF[((ks*8+mt)*64 + lane)*8 + e] = W[(32ks+8(lane>>4)+e)*128 + 16mt+(lane&15)]
//           WwT = bf16 row-transposed [128][256] (for k3's LDS GEMM).
// K1:       H = relu(table @ Wn + bn) -> bf16 [V][128]   (blocks < splitH)
//           nodeh = relu(table[node_ids] @ Wq + bq) -> nh[:,0:128] (rest)
//           no LDS, no barriers; wave = 16-row tile stream; W frags +
//           bias read from global (L1-hot); acc 32 + a 16 regs.
// K2 agg:   nh[:,128:256] = sum_t alpha * H[neigh]  (gather-FMA)
// K3 emb:   embb = relu(nh @ Ww + bw) bf16 + sumsq partials (r5 kernel)
// K5 final: out = relu(scale*(embb @ Wg) + bg) fp32; inline partials
//           reduce; same zero-LDS structure.
//
// MFMA orientation (verified r3..r12, numerics identical to r7's passing
// path): acc[mt] = mfma(wfrag, afrag, acc) -> lane l holds
// C[row = tile*16 + (l&15)][cols 16*mt + 4*(l>>4) + i].

using f32x4  = __attribute__((ext_vector_type(4))) float;
using short8 = __attribute__((ext_vector_type(8))) short;   // 8 bf16

__device__ __forceinline__ ushort f2bf(float f) {
    uint u = __float_as_uint(f);
    return (ushort)((u + 0x7fffu + ((u >> 16) & 1u)) >> 16);   // RNE
}
__device__ __forceinline__ float bf2f(ushort h) {
    return __uint_as_float((uint)h << 16);
}
__device__ __forceinline__ uint pk2(float lo, float hi) {
    return (uint)f2bf(lo) | ((uint)f2bf(hi) << 16);
}
__device__ __forceinline__ short8 pack8(f32x4 a, f32x4 b) {
    uint4 r;
    r.x = pk2(a[0], a[1]); r.y = pk2(a[2], a[3]);
    r.z = pk2(b[0], b[1]); r.w = pk2(b[2], b[3]);
    union { uint4 u; short8 s; } cv; cv.u = r; return cv.s;
}

// ---------------------------------------------------------------------------
// Prep: Wq/Wn/Wg -> fragment-linear bf16; Ww -> transposed bf16 [128][256].
// ---------------------------------------------------------------------------
__global__ __launch_bounds__(256)
void prep_weights(const float* __restrict__ Wq, const float* __restrict__ Wn,
                  const float* __restrict__ Ww, const float* __restrict__ Wg,
                  ushort* __restrict__ WqF, ushort* __restrict__ WnF,
                  ushort* __restrict__ WwT, ushort* __restrict__ WgF)
{
    int j = blockIdx.x * 256 + threadIdx.x;     // 320 blocks -> 81920
    if (j < 65536 && j >= 32768) {              // Ww: plain transpose [n][k]
        int t = j - 32768;                      // t = k*128 + n
        int n = t & 127, k = t >> 7;
        WwT[(size_t)n * 256 + k] = f2bf(Ww[t]);
        return;
    }
    const float* W; ushort* WF;
    int e_out = j;
    if (j < 16384)      { W = Wq; WF = WqF; }
    else if (j < 32768) { W = Wn; WF = WnF; e_out -= 16384; }
    else                { W = Wg; WF = WgF; e_out -= 65536; }
    int c = e_out >> 3, e = e_out & 7;
    int mtks = c >> 6, lane = c & 63;
    int ks = mtks >> 3, mt = mtks & 7;
    int l16 = lane & 15, lh = lane >> 4;
    WF[e_out] = f2bf(W[(size_t)(32 * ks + 8 * lh + e) * 128 + 16 * mt + l16]);
}

// ---------------------------------------------------------------------------
// K1: zero-LDS dual GEMM.
// ---------------------------------------------------------------------------
__global__ __launch_bounds__(256, 6)
void k1_nolds(const float* __restrict__ table, const int* __restrict__ node_ids,
              const ushort* __restrict__ WnF, const float* __restrict__ bn,
              const ushort* __restrict__ WqF, const float* __restrict__ bq,
              ushort* __restrict__ H, ushort* __restrict__ nh,
              int V, int N, int splitH)
{
    const int tid = threadIdx.x;
    const int w = tid >> 6, l = tid & 63, l16 = l & 15, lh = l >> 4;
    const bool isH = (int)blockIdx.x < splitH;

    const ushort* WF   = isH ? WnF : WqF;
    const float*  bias = isH ? bn : bq;
    const int M   = isH ? V : N;
    ushort* out   = isH ? H : nh;
    const int ldo = isH ? 128 : 256;
    const int nt  = (M + 15) >> 4;
    const int wid = (isH ? (int)blockIdx.x : (int)blockIdx.x - splitH) * 4 + w;
    const int nwv = (isH ? splitH : (int)gridDim.x - splitH) * 4;

    const ushort* wbase = WF + (size_t)l * 8;   // lane base; chunk stride 512

    for (int tile = wid; tile < nt; tile += nwv) {
        const int row = tile * 16 + l16;
        int g = (row < M) ? row : (M - 1);
        if (!isH) g = node_ids[g];
        const float* rp = table + (size_t)g * 128 + 8 * lh;

        short8 a[4];
#pragma unroll
        for (int ks = 0; ks < 4; ++ks) {
            f32x4 c0 = *reinterpret_cast<const f32x4*>(rp + 32 * ks);
            f32x4 c1 = *reinterpret_cast<const f32x4*>(rp + 32 * ks + 4);
            a[ks] = pack8(c0, c1);
        }

        f32x4 acc[8];
#pragma unroll
        for (int mt = 0; mt < 8; ++mt)
#pragma unroll
            for (int i = 0; i < 4; ++i) acc[mt][i] = 0.f;
#pragma unroll
        for (int ks = 0; ks < 4; ++ks)
#pragma unroll
            for (int mt = 0; mt < 8; ++mt) {
                short8 wf = *reinterpret_cast<const short8*>(
                    wbase + (size_t)(ks * 8 + mt) * 512);
                acc[mt] = __builtin_amdgcn_mfma_f32_16x16x32_bf16(wf, a[ks], acc[mt], 0, 0, 0);
            }

        if (row < M) {
#pragma unroll
            for (int mt = 0; mt < 8; ++mt) {
                f32x4 bv = *reinterpret_cast<const f32x4*>(&bias[16 * mt + 4 * lh]);
                uint2 q;
                q.x = pk2(fmaxf(acc[mt][0] + bv[0], 0.f), fmaxf(acc[mt][1] + bv[1], 0.f));
                q.y = pk2(fmaxf(acc[mt][2] + bv[2], 0.f), fmaxf(acc[mt][3] + bv[3], 0.f));
                *reinterpret_cast<uint2*>(&out[(size_t)row * ldo + 16 * mt + 4 * lh]) = q;
            }
        }
    }
}

// ---------------------------------------------------------------------------
// K2: agg[n][:] = sum_t alpha[n,t] * H[neigh_ids[n,t]][:]
// ---------------------------------------------------------------------------
__global__ __launch_bounds__(256)
void agg_bf16(const ushort* __restrict__ H,
              const int* __restrict__ nids,
              const float* __restrict__ alpha,
              ushort* __restrict__ outb,     // nh + 128, row stride 256
              int N)
{
    const int n   = blockIdx.x * 16 + (threadIdx.x >> 4);
    const int l16 = threadIdx.x & 15;
    if (n >= N) return;

    const int*   idp = &nids[n * 20];
    const float* alp = &alpha[n * 20];
    float a[8];
#pragma unroll
    for (int j = 0; j < 8; ++j) a[j] = 0.f;
#pragma unroll
    for (int t = 0; t < 20; ++t) {
        const int   id = idp[t];
        const float al = alp[t];
        uint4 h = *reinterpret_cast<const uint4*>(&H[(size_t)id * 128 + 8 * l16]);
        a[0] = fmaf(al, bf2f((ushort)(h.x & 0xffff)), a[0]);
        a[1] = fmaf(al, bf2f((ushort)(h.x >> 16)),    a[1]);
        a[2] = fmaf(al, bf2f((ushort)(h.y & 0xffff)), a[2]);
        a[3] = fmaf(al, bf2f((ushort)(h.y >> 16)),    a[3]);
        a[4] = fmaf(al, bf2f((ushort)(h.z & 0xffff)), a[4]);
        a[5] = fmaf(al, bf2f((ushort)(h.z >> 16)),    a[5]);
        a[6] = fmaf(al, bf2f((ushort)(h.w & 0xffff)), a[6]);
        a[7] = fmaf(al, bf2f((ushort)(h.w >> 16)),    a[7]);
    }
    uint4 p;
    p.x = pk2(a[0], a[1]); p.y = pk2(a[2], a[3]);
    p.z = pk2(a[4], a[5]); p.w = pk2(a[6], a[7]);
    *reinterpret_cast<uint4*>(&outb[(size_t)n * 256 + 8 * l16]) = p;
}

// ---------------------------------------------------------------------------
// K3: r5 LDS-staged MFMA GEMM, K=256 (nh bf16 -> embb bf16 + sumsq).
// ---------------------------------------------------------------------------
__global__ __launch_bounds__(256, 2)
void k3_emb(const ushort* __restrict__ nh, const ushort* __restrict__ WT,
            const float* __restrict__ bias, ushort* __restrict__ embb,
            float* __restrict__ partials, int M)
{
    __shared__ __align__(16) char smem[65536];  // A: [0,32K)  B: [32K,64K)
    __shared__ float red[256];
    char* Bbase = smem + 32768;
    const int KTOT = 256, lda = 256, ldo = 128;

    const int tid = threadIdx.x;
    const int w   = tid >> 6;
    const int l   = tid & 63;
    const int l16 = l & 15, lh = l >> 4;
    const int brow = blockIdx.x * 128;

    f32x4 acc[2][8];
#pragma unroll
    for (int fr = 0; fr < 2; ++fr)
#pragma unroll
        for (int fc = 0; fc < 8; ++fc)
#pragma unroll
            for (int i = 0; i < 4; ++i) acc[fr][fc][i] = 0.f;

    for (int k0 = 0; k0 < KTOT; k0 += 128) {
#pragma unroll
        for (int it = 0; it < 8; ++it) {
            int idx = it * 256 + tid;
            int r = idx >> 4, o = idx & 15;
            int row = brow + r; int grow = (row < M) ? row : (M - 1);
            uint4 v = *reinterpret_cast<const uint4*>(&nh[(size_t)grow * lda + k0 + 8 * o]);
            *reinterpret_cast<uint4*>(smem + r * 256 + ((16 * o) ^ ((r & 7) << 4))) = v;
        }
#pragma unroll
        for (int it = 0; it < 8; ++it) {
            int idx = it * 256 + tid;
            int n = idx >> 4, o = idx & 15;
            uint4 v = *reinterpret_cast<const uint4*>(&WT[(size_t)n * KTOT + k0 + 8 * o]);
            *reinterpret_cast<uint4*>(Bbase + n * 256 + ((16 * o) ^ ((n & 7) << 4))) = v;
        }
        __syncthreads();

        const int r0 = 32 * w + l16;
        const int r1 = r0 + 16;
#pragma unroll
        for (int ks = 0; ks < 4; ++ks) {
            const int kb = 64 * ks + 16 * lh;
            short8 a0 = *reinterpret_cast<const short8*>(
                smem + r0 * 256 + (kb ^ ((r0 & 7) << 4)));
            short8 a1 = *reinterpret_cast<const short8*>(
                smem + r1 * 256 + (kb ^ ((r1 & 7) << 4)));
#pragma unroll
            for (int fc = 0; fc < 8; ++fc) {
                const int nn = 16 * fc + l16;
                short8 b = *reinterpret_cast<const short8*>(
                    Bbase + nn * 256 + (kb ^ ((nn & 7) << 4)));
                acc[0][fc] = __builtin_amdgcn_mfma_f32_16x16x32_bf16(a0, b, acc[0][fc], 0, 0, 0);
                acc[1][fc] = __builtin_amdgcn_mfma_f32_16x16x32_bf16(a1, b, acc[1][fc], 0, 0, 0);
            }
        }
        __syncthreads();
    }

    float bloc[8];
#pragma unroll
    for (int fc = 0; fc < 8; ++fc) bloc[fc] = bias[16 * fc + l16];

    float ssq = 0.f;
#pragma unroll
    for (int fr = 0; fr < 2; ++fr)
#pragma unroll
        for (int fc = 0; fc < 8; ++fc)
#pragma unroll
            for (int i = 0; i < 4; ++i) {
                const int r   = 32 * w + 16 * fr + 4 * lh + i;
                const int col = 16 * fc + l16;
                float v = fmaxf(acc[fr][fc][i] + bloc[fc], 0.f);
                if (brow + r < M) ssq += v * v;
                ((ushort*)smem)[r * 128 + col] = f2bf(v);
            }
    __syncthreads();

#pragma unroll
    for (int it = 0; it < 8; ++it) {
        int idx = it * 256 + tid;
        int r = idx >> 4, o = idx & 15;
        if (brow + r < M)
            *reinterpret_cast<uint4*>(&embb[(size_t)(brow + r) * ldo + 8 * o]) =
                *reinterpret_cast<const uint4*>((ushort*)smem + r * 128 + 8 * o);
    }

    red[tid] = ssq;
    __syncthreads();
    for (int st = 128; st > 0; st >>= 1) {
        if (tid < st) red[tid] += red[tid + st];
        __syncthreads();
    }
    if (tid == 0) partials[blockIdx.x] = red[0];
}

// ---------------------------------------------------------------------------
// K5: zero-LDS final GEMM + inline norm reduce. A bf16 (embb), out fp32.
// ---------------------------------------------------------------------------
__global__ __launch_bounds__(256, 6)
void k5_final(const ushort* __restrict__ embb, const ushort* __restrict__ WgF,
              const float* __restrict__ bg, const float* __restrict__ partials,
              int P, float* __restrict__ outp, int N)
{
    __shared__ float red[256];
    __shared__ float s_scale;
    const int tid = threadIdx.x;
    const int w = tid >> 6, l = tid & 63, l16 = l & 15, lh = l >> 4;

    float s = 0.f;
    for (int i = tid; i < P; i += 256) s += partials[i];
    red[tid] = s;
    __syncthreads();
    for (int st = 128; st > 0; st >>= 1) {
        if (tid < st) red[tid] += red[tid + st];
        __syncthreads();
    }
    if (tid == 0) s_scale = 1.0f / sqrtf(red[0]);
    __syncthreads();
    const float scale = s_scale;

    const int nt = (N + 15) >> 4;
    const int wid = (int)blockIdx.x * 4 + w;
    const int nwv = (int)gridDim.x * 4;
    const ushort* wbase = WgF + (size_t)l * 8;

    for (int tile = wid; tile < nt; tile += nwv) {
        const int row = tile * 16 + l16;
        const int g = (row < N) ? row : (N - 1);
        const ushort* rp = embb + (size_t)g * 128 + 8 * lh;

        short8 a[4];
#pragma unroll
        for (int ks = 0; ks < 4; ++ks)
            a[ks] = *reinterpret_cast<const short8*>(rp + 32 * ks);

        f32x4 acc[8];
#pragma unroll
        for (int mt = 0; mt < 8; ++mt)
#pragma unroll
            for (int i = 0; i < 4; ++i) acc[mt][i] = 0.f;
#pragma unroll
        for (int ks = 0; ks < 4; ++ks)
#pragma unroll
            for (int mt = 0; mt < 8; ++mt) {
                short8 wf = *reinterpret_cast<const short8*>(
                    wbase + (size_t)(ks * 8 + mt) * 512);
                acc[mt] = __builtin_amdgcn_mfma_f32_16x16x32_bf16(wf, a[ks], acc[mt], 0, 0, 0);
            }

        if (row < N) {
#pragma unroll
            for (int mt = 0; mt < 8; ++mt) {
                f32x4 bv = *reinterpret_cast<const f32x4*>(&bg[16 * mt + 4 * lh]);
                f32x4 v;
#pragma unroll
                for (int i = 0; i < 4; ++i)
                    v[i] = fmaxf(fmaf(acc[mt][i], scale, bv[i]), 0.f);
                *reinterpret_cast<f32x4*>(&outp[(size_t)row * 128 + 16 * mt + 4 * lh]) = v;
            }
        }
    }
}

// ---------------------------------------------------------------------------
extern "C" void kernel_launch(void* const* d_in, const int* in_sizes, int n_in,
                              void* d_out, int out_size, void* d_ws, size_t ws_size,
                              hipStream_t stream)
{
    const int*   node_ids  = (const int*)  d_in[0];
    const int*   neigh_ids = (const int*)  d_in[1];
    const float* alpha     = (const float*)d_in[2];
    const float* table     = (const float*)d_in[3];
    const float* Wq        = (const float*)d_in[4];
    const float* bq        = (const float*)d_in[5];
    const float* Wn        = (const float*)d_in[6];
    const float* bn        = (const float*)d_in[7];
    const float* Ww        = (const float*)d_in[8];
    const float* bw        = (const float*)d_in[9];
    const float* Wg        = (const float*)d_in[10];
    const float* bg        = (const float*)d_in[11];

    const int N = in_sizes[0];            // 50000
    const int V = in_sizes[3] / 128;      // 200000
    float* out = (float*)d_out;

    // workspace layout
    ushort* H    = (ushort*)d_ws;                 // [V][128] bf16
    ushort* nh   = H    + (size_t)V * 128;        // [N][256] = [node_h | agg]
    ushort* embb = nh   + (size_t)N * 256;        // [N][128]
    ushort* WqF  = embb + (size_t)N * 128;        // frag-linear 16384
    ushort* WnF  = WqF  + 16384;
    ushort* WwT  = WnF  + 16384;                  // [128][256]
    ushort* WgF  = WwT  + 32768;
    float*  partials = (float*)(WgF + 16384);     // 512
    float*  scale    = partials + 512;

    const size_t need = (size_t)((char*)(scale + 16) - (char*)d_ws);
    if (ws_size < need) return;

    const int nblkN = (N + 127) / 128;

    // K1 grid: 1536 blocks (6/CU at 24 waves/CU), split by 16-row tiles.
    const int G1 = 1536;
    const long long tH = (V + 15) / 16, tN = (N + 15) / 16;
    int splitH = (int)((G1 * tH) / (tH + tN));
    if (splitH < 1) splitH = 1;
    if (splitH > G1 - 1) splitH = G1 - 1;

    prep_weights<<<320, 256, 0, stream>>>(Wq, Wn, Ww, Wg, WqF, WnF, WwT, WgF);
    k1_nolds<<<G1, 256, 0, stream>>>(table, node_ids, WnF, bn, WqF, bq,
                                     H, nh, V, N, splitH);
    agg_bf16<<<(N + 15) / 16, 256, 0, stream>>>(H, neigh_ids, alpha, nh + 128, N);
    k3_emb<<<nblkN, 256, 0, stream>>>(nh, WwT, bw, embb, partials, N);
    k5_final<<<768, 256, 0, stream>>>(embb, WgF, bg, partials, nblkN, out, N);
}